// Round 1
// baseline (492.607 us; speedup 1.0000x reference)
//
#include <hip/hip_runtime.h>
#include <hip/hip_bf16.h>

// GAT layer, N=8192, F=128.
//   k0: u = W@a1, v = W@a2                     (fp32, 1 CU-trivial)
//   k1: Wh = h@W -> WhT (bf16 [F][N]); e_src = h@u, e_dst = h@v (fp32)
//   k2: fused masked-softmax(P) @ Wh via MFMA bf16, denom in registers
//
// ws layout: [0, 2MB) WhT bf16 | u[128] | v[128] | e_src[8192] | e_dst[8192]

#define NN 8192
#define FF 128

typedef __bf16 bf16x8 __attribute__((ext_vector_type(8)));
typedef float floatx4 __attribute__((ext_vector_type(4)));

__device__ __forceinline__ unsigned short f2b(float f) {
    // fp32 -> bf16 round-to-nearest-even
    unsigned int u = __float_as_uint(f);
    return (unsigned short)((u + 0x7FFFu + ((u >> 16) & 1u)) >> 16);
}

// ---------------- k0: u = W@a1, v = W@a2 ----------------
__global__ __launch_bounds__(128) void k0_uv(const float* __restrict__ W,
                                             const float* __restrict__ a,
                                             float* __restrict__ u,
                                             float* __restrict__ v) {
    int k = blockIdx.x, t = threadIdx.x;
    float wv = W[k * FF + t];
    float p1 = wv * a[t];
    float p2 = wv * a[FF + t];
    for (int off = 32; off; off >>= 1) {
        p1 += __shfl_down(p1, off);
        p2 += __shfl_down(p2, off);
    }
    __shared__ float r[4];
    if ((t & 63) == 0) { r[(t >> 6) * 2] = p1; r[(t >> 6) * 2 + 1] = p2; }
    __syncthreads();
    if (t == 0) { u[k] = r[0] + r[2]; v[k] = r[1] + r[3]; }
}

// ---------------- k1: WhT (bf16) + e_src/e_dst (fp32) ----------------
// 256 blocks x 256 threads, 32 rows per block.
__global__ __launch_bounds__(256) void k1_wh(const float* __restrict__ h,
                                             const float* __restrict__ W,
                                             const float* __restrict__ u,
                                             const float* __restrict__ v,
                                             unsigned short* __restrict__ WhT,
                                             float* __restrict__ e_src,
                                             float* __restrict__ e_dst) {
    __shared__ float hL[32 * 132];          // [row][k], pitch 132 (16B-aligned rows)
    __shared__ float wL[128 * 132];         // [k][f]
    __shared__ float uL[128], vL[128];
    __shared__ unsigned short tL[128 * 40]; // bf16 [f][i], pitch 40 (16B-aligned)

    int t = threadIdx.x;
    int i0 = blockIdx.x * 32;

    { // stage h rows (32x128)
        int row = t >> 3, c = (t & 7) * 16;
        const float4* s = (const float4*)&h[(i0 + row) * FF + c];
        float4* d = (float4*)&hL[row * 132 + c];
        #pragma unroll
        for (int j = 0; j < 4; j++) d[j] = s[j];
    }
    { // stage W (128x128)
        int row = t >> 1, c = (t & 1) * 64;
        const float4* s = (const float4*)&W[row * FF + c];
        float4* d = (float4*)&wL[row * 132 + c];
        #pragma unroll
        for (int j = 0; j < 16; j++) d[j] = s[j];
    }
    if (t < 128) { uL[t] = u[t]; vL[t] = v[t]; }
    __syncthreads();

    int r0 = (t & 7) * 4;        // 4 rows
    int c0 = (t >> 3) * 4;       // 4 cols
    float acc[4][4] = {};
    for (int k0 = 0; k0 < 128; k0 += 4) {
        float4 hr[4], wr[4];
        #pragma unroll
        for (int i = 0; i < 4; i++) hr[i] = *(const float4*)&hL[(r0 + i) * 132 + k0];
        #pragma unroll
        for (int i = 0; i < 4; i++) wr[i] = *(const float4*)&wL[(k0 + i) * 132 + c0];
        #pragma unroll
        for (int kj = 0; kj < 4; kj++) {
            const float* hv0 = (const float*)&hr[0];
            #pragma unroll
            for (int ri = 0; ri < 4; ri++) {
                float hvv = ((const float*)&hr[ri])[kj];
                const float* wvv = (const float*)&wr[kj];
                #pragma unroll
                for (int cj = 0; cj < 4; cj++) acc[ri][cj] = fmaf(hvv, wvv[cj], acc[ri][cj]);
            }
            (void)hv0;
        }
    }
    // transpose-stage to bf16 [f][i]
    #pragma unroll
    for (int ri = 0; ri < 4; ri++)
        #pragma unroll
        for (int cj = 0; cj < 4; cj++)
            tL[(c0 + cj) * 40 + r0 + ri] = f2b(acc[ri][cj]);
    __syncthreads();

    // e_src / e_dst (fp32, from h and u/v directly)
    if (t < 64) {
        int row = t & 31;
        const float* sv = (t < 32) ? uL : vL;
        float s = 0.f;
        for (int k = 0; k < 128; k += 4) {
            float4 h4 = *(const float4*)&hL[row * 132 + k];
            float4 s4 = *(const float4*)&sv[k];
            s = fmaf(h4.x, s4.x, s); s = fmaf(h4.y, s4.y, s);
            s = fmaf(h4.z, s4.z, s); s = fmaf(h4.w, s4.w, s);
        }
        (t < 32 ? e_src : e_dst)[i0 + row] = s;
    }
    // WhT writeback (coalesced 32B per thread)
    {
        int f = t & 127, half = t >> 7;
        const uint4* s = (const uint4*)&tL[f * 40 + half * 16];
        uint4* d = (uint4*)&WhT[f * NN + i0 + half * 16];
        d[0] = s[0]; d[1] = s[1];
    }
}

// ---------------- k2: fused masked softmax @ Wh ----------------
// 256 blocks x 512 threads (8 waves). BM=32 rows, BN=128 (16 cols/wave), BK=64.
__device__ __forceinline__ float mask_w(int a, float x) {
    float l = fmaxf(x, 0.2f * x);          // LeakyReLU(0.2)
    return a > 0 ? __expf(l) : 0.f;
}

__global__ __launch_bounds__(512) void k2_gat(const int* __restrict__ adj,
                                              const unsigned short* __restrict__ WhT,
                                              const float* __restrict__ e_src,
                                              const float* __restrict__ e_dst,
                                              float* __restrict__ out) {
    __shared__ unsigned short wt[32 * 72];  // P tile bf16, pitch 72 (144B rows, 16B-aligned)
    __shared__ float esL[32];
    __shared__ float dpart[32 * 16];
    __shared__ float denomL[32];

    int t = threadIdx.x;
    int i0 = blockIdx.x * 32;
    if (t < 32) esL[t] = e_src[i0 + t];

    int ii = t & 31;          // P-tile row this thread fills
    int q  = t >> 5;          // 0..15 -> 4 js each
    int jj0 = q * 4;
    int lane = t & 63, wave = t >> 6;
    int mrow = lane & 15, quad = lane >> 4;
    int n0 = wave * 16;       // output-column tile of this wave

    const unsigned short* Bbase = WhT + (size_t)(n0 + mrow) * NN + quad * 8;
    const int* Abase = adj + (size_t)(i0 + ii) * NN + jj0;

    floatx4 acc0 = {0.f, 0.f, 0.f, 0.f};
    floatx4 acc1 = {0.f, 0.f, 0.f, 0.f};
    float dsum = 0.f;
    __syncthreads();
    float es_i = esL[ii];

    for (int j0 = 0; j0 < NN; j0 += 64) {
        int4 av = *(const int4*)(Abase + j0);
        float4 ed = *(const float4*)&e_dst[j0 + jj0];
        // B fragments: global (L2-resident WhT), independent of LDS barrier
        bf16x8 b0 = *(const bf16x8*)(Bbase + j0);
        bf16x8 b1 = *(const bf16x8*)(Bbase + j0 + 32);

        float w0 = mask_w(av.x, es_i + ed.x);
        float w1 = mask_w(av.y, es_i + ed.y);
        float w2 = mask_w(av.z, es_i + ed.z);
        float w3 = mask_w(av.w, es_i + ed.w);
        dsum += (w0 + w1) + (w2 + w3);
        ushort4 wp = make_ushort4(f2b(w0), f2b(w1), f2b(w2), f2b(w3));

        __syncthreads();                    // prior iteration's A-frag reads done
        *(ushort4*)&wt[ii * 72 + jj0] = wp;
        __syncthreads();                    // P tile visible

        bf16x8 a00 = *(const bf16x8*)&wt[mrow * 72 + quad * 8];
        bf16x8 a10 = *(const bf16x8*)&wt[(16 + mrow) * 72 + quad * 8];
        bf16x8 a01 = *(const bf16x8*)&wt[mrow * 72 + 32 + quad * 8];
        bf16x8 a11 = *(const bf16x8*)&wt[(16 + mrow) * 72 + 32 + quad * 8];

        acc0 = __builtin_amdgcn_mfma_f32_16x16x32_bf16(a00, b0, acc0, 0, 0, 0);
        acc1 = __builtin_amdgcn_mfma_f32_16x16x32_bf16(a10, b0, acc1, 0, 0, 0);
        acc0 = __builtin_amdgcn_mfma_f32_16x16x32_bf16(a01, b1, acc0, 0, 0, 0);
        acc1 = __builtin_amdgcn_mfma_f32_16x16x32_bf16(a11, b1, acc1, 0, 0, 0);
    }

    dpart[ii * 16 + q] = dsum;
    __syncthreads();
    if (t < 32) {
        float s = 0.f;
        #pragma unroll
        for (int k = 0; k < 16; k++) s += dpart[t * 16 + k];
        denomL[t] = 1.0f / s;
    }
    __syncthreads();

    // C/D layout (16x16x32): col = lane&15, row = (lane>>4)*4 + reg
    #pragma unroll
    for (int r = 0; r < 4; r++) {
        int row0 = quad * 4 + r;
        out[(i0 + row0) * FF + n0 + mrow] = acc0[r] * denomL[row0];
        int row1 = 16 + row0;
        out[(i0 + row1) * FF + n0 + mrow] = acc1[r] * denomL[row1];
    }
}

extern "C" void kernel_launch(void* const* d_in, const int* in_sizes, int n_in,
                              void* d_out, int out_size, void* d_ws, size_t ws_size,
                              hipStream_t stream) {
    const float* h   = (const float*)d_in[0];
    const int*   adj = (const int*)d_in[1];
    const float* W   = (const float*)d_in[2];
    const float* a   = (const float*)d_in[3];
    float* out = (float*)d_out;

    char* ws = (char*)d_ws;
    unsigned short* WhT = (unsigned short*)ws;              // 2 MB bf16 [F][N]
    float* u     = (float*)(ws + 2097152);
    float* v     = u + 128;
    float* e_src = v + 128;
    float* e_dst = e_src + NN;

    k0_uv<<<dim3(128), dim3(128), 0, stream>>>(W, a, u, v);
    k1_wh<<<dim3(256), dim3(256), 0, stream>>>(h, W, u, v, WhT, e_src, e_dst);
    k2_gat<<<dim3(256), dim3(512), 0, stream>>>(adj, WhT, e_src, e_dst, out);
}

// Round 2
// 419.302 us; speedup vs baseline: 1.1748x; 1.1748x over previous
//
#include <hip/hip_runtime.h>
#include <hip/hip_bf16.h>

// GAT layer, N=8192, F=128.
//   k0: u = W@a1, v = W@a2                     (fp32, trivial)
//   k1: Wh = h@W -> WhT (bf16 [F][N]); e_src = h@u, e_dst = h@v (fp32)
//   k2: fused masked-softmax(P) @ Wh via MFMA bf16, j split 4-ways across
//       blocks; numerator atomicAdd into d_out, denominator into ws.
//       Double-buffered XOR-swizzled P tile, 1 barrier/iter, prefetch d=1.
//   k3: out[i][:] *= 1/den[i]
//
// ws: [0,2MB) WhT bf16 | u[128] | v[128] | e_src[8192] | e_dst[8192] | den[8192]

#define NN 8192
#define FF 128
#define SEG 4
#define JSEG (NN / SEG)      // 2048
#define ITERS (JSEG / 64)    // 32

typedef __bf16 bf16x8 __attribute__((ext_vector_type(8)));
typedef float floatx4 __attribute__((ext_vector_type(4)));

__device__ __forceinline__ unsigned short f2b(float f) {
    unsigned int u = __float_as_uint(f);
    return (unsigned short)((u + 0x7FFFu + ((u >> 16) & 1u)) >> 16);
}

// ---------------- k0 ----------------
__global__ __launch_bounds__(128) void k0_uv(const float* __restrict__ W,
                                             const float* __restrict__ a,
                                             float* __restrict__ u,
                                             float* __restrict__ v) {
    int k = blockIdx.x, t = threadIdx.x;
    float wv = W[k * FF + t];
    float p1 = wv * a[t];
    float p2 = wv * a[FF + t];
    for (int off = 32; off; off >>= 1) {
        p1 += __shfl_down(p1, off);
        p2 += __shfl_down(p2, off);
    }
    __shared__ float r[4];
    if ((t & 63) == 0) { r[(t >> 6) * 2] = p1; r[(t >> 6) * 2 + 1] = p2; }
    __syncthreads();
    if (t == 0) { u[k] = r[0] + r[2]; v[k] = r[1] + r[3]; }
}

// ---------------- k1 ----------------
__global__ __launch_bounds__(256) void k1_wh(const float* __restrict__ h,
                                             const float* __restrict__ W,
                                             const float* __restrict__ u,
                                             const float* __restrict__ v,
                                             unsigned short* __restrict__ WhT,
                                             float* __restrict__ e_src,
                                             float* __restrict__ e_dst) {
    __shared__ float hL[32 * 132];
    __shared__ float wL[128 * 132];
    __shared__ float uL[128], vL[128];
    __shared__ unsigned short tL[128 * 40];

    int t = threadIdx.x;
    int i0 = blockIdx.x * 32;

    {
        int row = t >> 3, c = (t & 7) * 16;
        const float4* s = (const float4*)&h[(i0 + row) * FF + c];
        float4* d = (float4*)&hL[row * 132 + c];
        #pragma unroll
        for (int j = 0; j < 4; j++) d[j] = s[j];
    }
    {
        int row = t >> 1, c = (t & 1) * 64;
        const float4* s = (const float4*)&W[row * FF + c];
        float4* d = (float4*)&wL[row * 132 + c];
        #pragma unroll
        for (int j = 0; j < 16; j++) d[j] = s[j];
    }
    if (t < 128) { uL[t] = u[t]; vL[t] = v[t]; }
    __syncthreads();

    int r0 = (t & 7) * 4;
    int c0 = (t >> 3) * 4;
    float acc[4][4] = {};
    for (int k0 = 0; k0 < 128; k0 += 4) {
        float4 hr[4], wr[4];
        #pragma unroll
        for (int i = 0; i < 4; i++) hr[i] = *(const float4*)&hL[(r0 + i) * 132 + k0];
        #pragma unroll
        for (int i = 0; i < 4; i++) wr[i] = *(const float4*)&wL[(k0 + i) * 132 + c0];
        #pragma unroll
        for (int kj = 0; kj < 4; kj++) {
            #pragma unroll
            for (int ri = 0; ri < 4; ri++) {
                float hvv = ((const float*)&hr[ri])[kj];
                const float* wvv = (const float*)&wr[kj];
                #pragma unroll
                for (int cj = 0; cj < 4; cj++) acc[ri][cj] = fmaf(hvv, wvv[cj], acc[ri][cj]);
            }
        }
    }
    #pragma unroll
    for (int ri = 0; ri < 4; ri++)
        #pragma unroll
        for (int cj = 0; cj < 4; cj++)
            tL[(c0 + cj) * 40 + r0 + ri] = f2b(acc[ri][cj]);
    __syncthreads();

    if (t < 64) {
        int row = t & 31;
        const float* sv = (t < 32) ? uL : vL;
        float s = 0.f;
        for (int k = 0; k < 128; k += 4) {
            float4 h4 = *(const float4*)&hL[row * 132 + k];
            float4 s4 = *(const float4*)&sv[k];
            s = fmaf(h4.x, s4.x, s); s = fmaf(h4.y, s4.y, s);
            s = fmaf(h4.z, s4.z, s); s = fmaf(h4.w, s4.w, s);
        }
        (t < 32 ? e_src : e_dst)[i0 + row] = s;
    }
    {
        int f = t & 127, half = t >> 7;
        const uint4* s = (const uint4*)&tL[f * 40 + half * 16];
        uint4* d = (uint4*)&WhT[f * NN + i0 + half * 16];
        d[0] = s[0]; d[1] = s[1];
    }
}

// ---------------- k2 ----------------
__device__ __forceinline__ float mask_w(int a, float x) {
    float l = fmaxf(x, 0.2f * x);
    return a > 0 ? __expf(l) : 0.f;
}

__global__ __launch_bounds__(512, 4) void k2_gat(const int* __restrict__ adj,
                                                 const unsigned short* __restrict__ WhT,
                                                 const float* __restrict__ e_src,
                                                 const float* __restrict__ e_dst,
                                                 float* __restrict__ num,
                                                 float* __restrict__ den) {
    __shared__ unsigned short wt[2][32 * 64];   // XOR-swizzled P tiles, 4 KB each
    __shared__ float esL[32];
    __shared__ float dpart[32 * 17];

    int t = threadIdx.x;
    int bx = blockIdx.x;
    int g = bx >> 2, seg = bx & 3;
    int i0 = g * 32;
    int jbase = seg * JSEG;

    if (t < 32) esL[t] = e_src[i0 + t];

    int ii = t & 31;
    int q  = t >> 5;                  // 0..15
    int lane = t & 63, wave = t >> 6;
    int mrow = lane & 15, quad = lane >> 4;
    int n0 = wave * 16;

    const unsigned short* Bb = WhT + (size_t)(n0 + mrow) * NN + jbase + quad * 8;
    const int*   Ab = adj + (size_t)(i0 + ii) * NN + jbase + q * 4;
    const float* Eb = e_dst + jbase + q * 4;

    // swizzled addresses (shorts): 8-col group gg stored at gg ^ (row & 7)
    int waddr = ii * 64 + (((q >> 1) ^ (ii & 7)) << 3) + ((q & 1) << 2);
    int ra00 = mrow * 64 + ((quad ^ (mrow & 7)) << 3);
    int ra01 = mrow * 64 + (((4 + quad) ^ (mrow & 7)) << 3);
    int ra10 = (16 + mrow) * 64 + ((quad ^ (mrow & 7)) << 3);
    int ra11 = (16 + mrow) * 64 + (((4 + quad) ^ (mrow & 7)) << 3);

    floatx4 acc0 = {0.f, 0.f, 0.f, 0.f};
    floatx4 acc1 = {0.f, 0.f, 0.f, 0.f};
    float dsum = 0.f;
    __syncthreads();
    float es_i = esL[ii];

    // prologue: iteration 0 -> buf 0
    int4   av = *(const int4*)Ab;
    float4 ed = *(const float4*)Eb;
    bf16x8 b0 = *(const bf16x8*)Bb;
    bf16x8 b1 = *(const bf16x8*)(Bb + 32);
    {
        float w0 = mask_w(av.x, es_i + ed.x);
        float w1 = mask_w(av.y, es_i + ed.y);
        float w2 = mask_w(av.z, es_i + ed.z);
        float w3 = mask_w(av.w, es_i + ed.w);
        dsum += (w0 + w1) + (w2 + w3);
        *(ushort4*)&wt[0][waddr] = make_ushort4(f2b(w0), f2b(w1), f2b(w2), f2b(w3));
    }
    __syncthreads();

    for (int k = 0; k < ITERS - 1; k++) {
        int joff = (k + 1) * 64;
        // prefetch iteration k+1
        int4   av2 = *(const int4*)(Ab + joff);
        float4 ed2 = *(const float4*)(Eb + joff);
        bf16x8 nb0 = *(const bf16x8*)(Bb + joff);
        bf16x8 nb1 = *(const bf16x8*)(Bb + joff + 32);

        // MFMA on iteration k
        const unsigned short* buf = wt[k & 1];
        bf16x8 a00 = *(const bf16x8*)&buf[ra00];
        bf16x8 a10 = *(const bf16x8*)&buf[ra10];
        bf16x8 a01 = *(const bf16x8*)&buf[ra01];
        bf16x8 a11 = *(const bf16x8*)&buf[ra11];
        acc0 = __builtin_amdgcn_mfma_f32_16x16x32_bf16(a00, b0, acc0, 0, 0, 0);
        acc1 = __builtin_amdgcn_mfma_f32_16x16x32_bf16(a10, b0, acc1, 0, 0, 0);
        acc0 = __builtin_amdgcn_mfma_f32_16x16x32_bf16(a01, b1, acc0, 0, 0, 0);
        acc1 = __builtin_amdgcn_mfma_f32_16x16x32_bf16(a11, b1, acc1, 0, 0, 0);

        // compute iteration k+1 weights -> other buffer
        float w0 = mask_w(av2.x, es_i + ed2.x);
        float w1 = mask_w(av2.y, es_i + ed2.y);
        float w2 = mask_w(av2.z, es_i + ed2.z);
        float w3 = mask_w(av2.w, es_i + ed2.w);
        dsum += (w0 + w1) + (w2 + w3);
        *(ushort4*)&wt[(k + 1) & 1][waddr] = make_ushort4(f2b(w0), f2b(w1), f2b(w2), f2b(w3));
        b0 = nb0; b1 = nb1;
        __syncthreads();
    }
    {
        const unsigned short* buf = wt[(ITERS - 1) & 1];
        bf16x8 a00 = *(const bf16x8*)&buf[ra00];
        bf16x8 a10 = *(const bf16x8*)&buf[ra10];
        bf16x8 a01 = *(const bf16x8*)&buf[ra01];
        bf16x8 a11 = *(const bf16x8*)&buf[ra11];
        acc0 = __builtin_amdgcn_mfma_f32_16x16x32_bf16(a00, b0, acc0, 0, 0, 0);
        acc1 = __builtin_amdgcn_mfma_f32_16x16x32_bf16(a10, b0, acc1, 0, 0, 0);
        acc0 = __builtin_amdgcn_mfma_f32_16x16x32_bf16(a01, b1, acc0, 0, 0, 0);
        acc1 = __builtin_amdgcn_mfma_f32_16x16x32_bf16(a11, b1, acc1, 0, 0, 0);
    }

    dpart[ii * 17 + q] = dsum;
    __syncthreads();
    if (t < 32) {
        float s = 0.f;
        #pragma unroll
        for (int k = 0; k < 16; k++) s += dpart[t * 17 + k];
        atomicAdd(&den[i0 + t], s);
    }

    // numerator merge: C/D layout col=lane&15, row=(lane>>4)*4+reg
    #pragma unroll
    for (int r = 0; r < 4; r++) {
        int row0 = quad * 4 + r;
        atomicAdd(&num[(size_t)(i0 + row0) * FF + n0 + mrow], acc0[r]);
        atomicAdd(&num[(size_t)(i0 + 16 + row0) * FF + n0 + mrow], acc1[r]);
    }
}

// ---------------- k3: out[i][:] /= den[i] ----------------
__global__ __launch_bounds__(256) void k3_scale(float* __restrict__ out,
                                                const float* __restrict__ den) {
    int idx = blockIdx.x * 256 + threadIdx.x;   // one float4 each
    int i = idx >> 5;
    int c = (idx & 31) << 2;
    float r = 1.0f / den[i];
    float4* p = (float4*)&out[(size_t)i * FF + c];
    float4 v = *p;
    v.x *= r; v.y *= r; v.z *= r; v.w *= r;
    *p = v;
}

extern "C" void kernel_launch(void* const* d_in, const int* in_sizes, int n_in,
                              void* d_out, int out_size, void* d_ws, size_t ws_size,
                              hipStream_t stream) {
    const float* h   = (const float*)d_in[0];
    const int*   adj = (const int*)d_in[1];
    const float* W   = (const float*)d_in[2];
    const float* a   = (const float*)d_in[3];
    float* out = (float*)d_out;

    char* ws = (char*)d_ws;
    unsigned short* WhT = (unsigned short*)ws;              // 2 MB bf16 [F][N]
    float* u     = (float*)(ws + 2097152);
    float* v     = u + 128;
    float* e_src = v + 128;
    float* e_dst = e_src + NN;
    float* den   = e_dst + NN;                              // 32 KB

    hipMemsetAsync(out, 0, (size_t)NN * FF * sizeof(float), stream);
    hipMemsetAsync(den, 0, (size_t)NN * sizeof(float), stream);

    k0_uv<<<dim3(128), dim3(128), 0, stream>>>(W, a, u, v);
    k1_wh<<<dim3(256), dim3(256), 0, stream>>>(h, W, u, v, WhT, e_src, e_dst);
    k2_gat<<<dim3(256 * SEG), dim3(512), 0, stream>>>(adj, WhT, e_src, e_dst, out, den);
    k3_scale<<<dim3(NN * FF / 4 / 256), dim3(256), 0, stream>>>(out, den);
}